// Round 2
// baseline (487.433 us; speedup 1.0000x reference)
//
#include <hip/hip_runtime.h>

// Instant-NGP multires hash encoding fwd. N=1M, L=16, F=2, T=2^19.
// R2: counting-sort points by res-16 cell so waves process spatially-local
// points -> divergent table gathers coalesce to shared cachelines.

__constant__ float c_res[16] = {
    16.f, 18.f, 21.f, 24.f, 27.f, 32.f, 36.f, 42.f,
    48.f, 55.f, 64.f, 73.f, 84.f, 97.f, 111.f, 128.f
};

#define TMASK  0x7FFFFu
#define PRIME1 2654435761u
#define PRIME2 805459861u
#define NBUCKET 4096

// ---- ws layout ----
// [0      , 16384)  hist (4096 u32)
// [16384  , 32768)  cursor (4096 u32)
// [32768  , 32768 + npts*16)  x4_sorted (float4: x,y,z, orig-idx bitcast)

__global__ void k_zero(unsigned* __restrict__ hist) {
    int i = blockIdx.x * 256 + threadIdx.x;
    if (i < NBUCKET) hist[i] = 0u;
}

__device__ __forceinline__ int bucket_of(float x0, float x1, float x2) {
    int c0 = (int)(x0 * 16.f); c0 = c0 < 0 ? 0 : (c0 > 15 ? 15 : c0);
    int c1 = (int)(x1 * 16.f); c1 = c1 < 0 ? 0 : (c1 > 15 ? 15 : c1);
    int c2 = (int)(x2 * 16.f); c2 = c2 < 0 ? 0 : (c2 > 15 ? 15 : c2);
    return (c0 << 8) | (c1 << 4) | c2;
}

__global__ void k_hist(const float* __restrict__ x, unsigned* __restrict__ hist,
                       int npts) {
    int i = blockIdx.x * 256 + threadIdx.x;
    if (i >= npts) return;
    int b = bucket_of(x[3 * i], x[3 * i + 1], x[3 * i + 2]);
    atomicAdd(&hist[b], 1u);
}

// One block, 1024 threads, scans 4096 histogram entries -> exclusive offsets.
__global__ void k_scan(const unsigned* __restrict__ hist,
                       unsigned* __restrict__ cursor) {
    __shared__ unsigned tmp[1024];
    int t = threadIdx.x;
    unsigned v0 = hist[t * 4 + 0], v1 = hist[t * 4 + 1];
    unsigned v2 = hist[t * 4 + 2], v3 = hist[t * 4 + 3];
    unsigned s = v0 + v1 + v2 + v3;
    tmp[t] = s;
    __syncthreads();
    for (int off = 1; off < 1024; off <<= 1) {
        unsigned u = (t >= off) ? tmp[t - off] : 0u;
        __syncthreads();
        tmp[t] += u;
        __syncthreads();
    }
    unsigned excl = tmp[t] - s;
    cursor[t * 4 + 0] = excl;
    cursor[t * 4 + 1] = excl + v0;
    cursor[t * 4 + 2] = excl + v0 + v1;
    cursor[t * 4 + 3] = excl + v0 + v1 + v2;
}

__global__ void k_scatter(const float* __restrict__ x,
                          unsigned* __restrict__ cursor,
                          float4* __restrict__ x4, int npts) {
    int i = blockIdx.x * 256 + threadIdx.x;
    if (i >= npts) return;
    float x0 = x[3 * i], x1 = x[3 * i + 1], x2 = x[3 * i + 2];
    int b = bucket_of(x0, x1, x2);
    unsigned pos = atomicAdd(&cursor[b], 1u);
    float4 v; v.x = x0; v.y = x1; v.z = x2; v.w = __int_as_float(i);
    x4[pos] = v;
}

// Compute one level's encoding for one point. 8 independent dwordx2 gathers.
__device__ __forceinline__ float2 enc_level(float x0, float x1, float x2,
                                            float r,
                                            const float2* __restrict__ tab) {
    float s0 = x0 * r, s1 = x1 * r, s2 = x2 * r;   // lone fp32 mul == numpy
    float f0 = floorf(s0), f1 = floorf(s1), f2 = floorf(s2);
    float d0 = s0 - f0, d1 = s1 - f1, d2 = s2 - f2;

    unsigned A0 = (unsigned)(int)f0;
    unsigned B0 = (unsigned)(int)ceilf(s0);
    unsigned A1 = (unsigned)(int)f1 * PRIME1;
    unsigned B1 = (unsigned)(int)ceilf(s1) * PRIME1;
    unsigned A2 = (unsigned)(int)f2 * PRIME2;
    unsigned B2 = (unsigned)(int)ceilf(s2) * PRIME2;

    unsigned h0 = (A0 ^ A1 ^ A2) & TMASK;
    unsigned h1 = (B0 ^ A1 ^ A2) & TMASK;
    unsigned h2 = (A0 ^ B1 ^ A2) & TMASK;
    unsigned h3 = (A0 ^ A1 ^ B2) & TMASK;
    unsigned h4 = (B0 ^ B1 ^ A2) & TMASK;
    unsigned h5 = (B0 ^ A1 ^ B2) & TMASK;
    unsigned h6 = (A0 ^ B1 ^ B2) & TMASK;
    unsigned h7 = (B0 ^ B1 ^ B2) & TMASK;

    float2 v0 = tab[h0], v1 = tab[h1], v2 = tab[h2], v3 = tab[h3];
    float2 v4 = tab[h4], v5 = tab[h5], v6 = tab[h6], v7 = tab[h7];

    float u0 = 1.f - d0, u1 = 1.f - d1, u2 = 1.f - d2;
    float w0 = u0 * u1 * u2, w1 = d0 * u1 * u2;
    float w2 = u0 * d1 * u2, w3 = u0 * u1 * d2;
    float w4 = d0 * d1 * u2, w5 = d0 * u1 * d2;
    float w6 = u0 * d1 * d2, w7 = d0 * d1 * d2;

    float ex = v0.x * w0, ey = v0.y * w0;
    ex += v1.x * w1;  ey += v1.y * w1;
    ex += v2.x * w2;  ey += v2.y * w2;
    ex += v3.x * w3;  ey += v3.y * w3;
    ex += v4.x * w4;  ey += v4.y * w4;
    ex += v5.x * w5;  ey += v5.y * w5;
    ex += v6.x * w6;  ey += v6.y * w6;
    ex += v7.x * w7;  ey += v7.y * w7;
    float2 o; o.x = ex; o.y = ey; return o;
}

// Main: each lane = one sorted point; loop over level pairs; store float4
// {lvl2j, lvl2j+1} to out row of the ORIGINAL point index.
__global__ __launch_bounds__(256)
void k_main(const float4* __restrict__ x4, const float2* __restrict__ tab,
            float4* __restrict__ out4, int npts) {
    int ps = blockIdx.x * 256 + threadIdx.x;   // sorted point index
    if (ps >= npts) return;
    float4 xo = x4[ps];
    float x0 = xo.x, x1 = xo.y, x2 = xo.z;
    unsigned orig = (unsigned)__float_as_int(xo.w);

    #pragma unroll 1
    for (int j = 0; j < 8; ++j) {
        float2 e0 = enc_level(x0, x1, x2, c_res[2 * j + 0], tab);
        float2 e1 = enc_level(x0, x1, x2, c_res[2 * j + 1], tab);
        float4 o; o.x = e0.x; o.y = e0.y; o.z = e1.x; o.w = e1.y;
        out4[orig * 8 + j] = o;
    }
}

// Fallback (R1 kernel) if ws is too small for the sort buffers.
__global__ __launch_bounds__(256, 8)
void k_fallback(const float* __restrict__ x, const float2* __restrict__ tab,
                float2* __restrict__ out, int total) {
    int tid = blockIdx.x * 256 + threadIdx.x;
    if (tid >= total) return;
    int p = tid >> 4, l = tid & 15;
    float2 e = enc_level(x[3 * p], x[3 * p + 1], x[3 * p + 2], c_res[l], tab);
    out[tid] = e;
}

extern "C" void kernel_launch(void* const* d_in, const int* in_sizes, int n_in,
                              void* d_out, int out_size, void* d_ws, size_t ws_size,
                              hipStream_t stream)
{
    const float*  x   = (const float*)d_in[0];
    const float2* tab = (const float2*)d_in[1];
    int npts = in_sizes[0] / 3;

    size_t need = 32768 + (size_t)npts * 16;
    if (ws_size < need) {
        int total = npts * 16;
        k_fallback<<<(total + 255) / 256, 256, 0, stream>>>(
            x, tab, (float2*)d_out, total);
        return;
    }

    unsigned* hist   = (unsigned*)d_ws;
    unsigned* cursor = (unsigned*)((char*)d_ws + 16384);
    float4*   x4     = (float4*)((char*)d_ws + 32768);

    k_zero<<<(NBUCKET + 255) / 256, 256, 0, stream>>>(hist);
    k_hist<<<(npts + 255) / 256, 256, 0, stream>>>(x, hist, npts);
    k_scan<<<1, 1024, 0, stream>>>(hist, cursor);
    k_scatter<<<(npts + 255) / 256, 256, 0, stream>>>(x, cursor, x4, npts);
    k_main<<<(npts + 255) / 256, 256, 0, stream>>>(x4, tab, (float4*)d_out, npts);
}

// Round 3
// 430.065 us; speedup vs baseline: 1.1334x; 1.1334x over previous
//
#include <hip/hip_runtime.h>

// Instant-NGP multires hash encoding fwd. N=1M, L=16, F=2, T=2^19.
// R3: counting-sort by 15-bit Morton key of res-32 cell (32768 buckets).
//   - 8x more buckets than R2 -> 8x shallower same-address atomic chains
//     in hist/scatter (R2's 262us pipeline overhead).
//   - Finer+Morton locality -> fewer unique table cachelines per wave
//     in k_main (model: ~170 vs ~421 lines per 64pts x 16 levels).

__constant__ float c_res[16] = {
    16.f, 18.f, 21.f, 24.f, 27.f, 32.f, 36.f, 42.f,
    48.f, 55.f, 64.f, 73.f, 84.f, 97.f, 111.f, 128.f
};

#define TMASK  0x7FFFFu
#define PRIME1 2654435761u
#define PRIME2 805459861u
#define NBUCKET 32768

// ---- ws layout ----
// [0, 128K)        hist   (32768 u32)
// [128K, 256K)     cursor (32768 u32)
// [256K, +npts*16) x4_sorted (float4: x,y,z, orig-idx bitcast)

__global__ void k_zero(unsigned* __restrict__ hist) {
    int i = blockIdx.x * 256 + threadIdx.x;
    if (i < NBUCKET) hist[i] = 0u;
}

// Spread 5-bit value to every 3rd bit: b4..b0 -> bits 12,9,6,3,0.
__device__ __forceinline__ unsigned part5(unsigned v) {
    v = (v | (v << 8)) & 0x100Fu;
    v = (v | (v << 4)) & 0x10C3u;
    v = (v | (v << 2)) & 0x1249u;
    return v;
}

__device__ __forceinline__ int bucket_of(float x0, float x1, float x2) {
    int c0 = (int)(x0 * 32.f); c0 = c0 < 0 ? 0 : (c0 > 31 ? 31 : c0);
    int c1 = (int)(x1 * 32.f); c1 = c1 < 0 ? 0 : (c1 > 31 ? 31 : c1);
    int c2 = (int)(x2 * 32.f); c2 = c2 < 0 ? 0 : (c2 > 31 ? 31 : c2);
    return (int)(part5((unsigned)c0) | (part5((unsigned)c1) << 1)
                 | (part5((unsigned)c2) << 2));
}

__global__ void k_hist(const float* __restrict__ x, unsigned* __restrict__ hist,
                       int npts) {
    int i = blockIdx.x * 256 + threadIdx.x;
    if (i >= npts) return;
    int b = bucket_of(x[3 * i], x[3 * i + 1], x[3 * i + 2]);
    atomicAdd(&hist[b], 1u);
}

// One block, 1024 threads, 32 buckets/thread -> exclusive scan of 32768.
__global__ __launch_bounds__(1024)
void k_scan(const unsigned* __restrict__ hist, unsigned* __restrict__ cursor) {
    __shared__ unsigned tmp[1024];
    int t = threadIdx.x;
    unsigned loc[32];
    unsigned s = 0;
    const uint4* h4 = (const uint4*)(hist + t * 32);
    #pragma unroll
    for (int i = 0; i < 8; ++i) {
        uint4 v = h4[i];
        loc[4 * i + 0] = s; s += v.x;
        loc[4 * i + 1] = s; s += v.y;
        loc[4 * i + 2] = s; s += v.z;
        loc[4 * i + 3] = s; s += v.w;
    }
    tmp[t] = s;
    __syncthreads();
    for (int off = 1; off < 1024; off <<= 1) {
        unsigned u = (t >= off) ? tmp[t - off] : 0u;
        __syncthreads();
        tmp[t] += u;
        __syncthreads();
    }
    unsigned excl = tmp[t] - s;
    uint4* c4 = (uint4*)(cursor + t * 32);
    #pragma unroll
    for (int i = 0; i < 8; ++i) {
        uint4 v;
        v.x = excl + loc[4 * i + 0];
        v.y = excl + loc[4 * i + 1];
        v.z = excl + loc[4 * i + 2];
        v.w = excl + loc[4 * i + 3];
        c4[i] = v;
    }
}

__global__ void k_scatter(const float* __restrict__ x,
                          unsigned* __restrict__ cursor,
                          float4* __restrict__ x4, int npts) {
    int i = blockIdx.x * 256 + threadIdx.x;
    if (i >= npts) return;
    float x0 = x[3 * i], x1 = x[3 * i + 1], x2 = x[3 * i + 2];
    int b = bucket_of(x0, x1, x2);
    unsigned pos = atomicAdd(&cursor[b], 1u);
    float4 v; v.x = x0; v.y = x1; v.z = x2; v.w = __int_as_float(i);
    x4[pos] = v;
}

// One level's encoding for one point. 8 independent dwordx2 gathers.
__device__ __forceinline__ float2 enc_level(float x0, float x1, float x2,
                                            float r,
                                            const float2* __restrict__ tab) {
    float s0 = x0 * r, s1 = x1 * r, s2 = x2 * r;   // lone fp32 mul == numpy
    float f0 = floorf(s0), f1 = floorf(s1), f2 = floorf(s2);
    float d0 = s0 - f0, d1 = s1 - f1, d2 = s2 - f2;

    unsigned A0 = (unsigned)(int)f0;
    unsigned B0 = (unsigned)(int)ceilf(s0);
    unsigned A1 = (unsigned)(int)f1 * PRIME1;
    unsigned B1 = (unsigned)(int)ceilf(s1) * PRIME1;
    unsigned A2 = (unsigned)(int)f2 * PRIME2;
    unsigned B2 = (unsigned)(int)ceilf(s2) * PRIME2;

    unsigned h0 = (A0 ^ A1 ^ A2) & TMASK;
    unsigned h1 = (B0 ^ A1 ^ A2) & TMASK;
    unsigned h2 = (A0 ^ B1 ^ A2) & TMASK;
    unsigned h3 = (A0 ^ A1 ^ B2) & TMASK;
    unsigned h4 = (B0 ^ B1 ^ A2) & TMASK;
    unsigned h5 = (B0 ^ A1 ^ B2) & TMASK;
    unsigned h6 = (A0 ^ B1 ^ B2) & TMASK;
    unsigned h7 = (B0 ^ B1 ^ B2) & TMASK;

    float2 v0 = tab[h0], v1 = tab[h1], v2 = tab[h2], v3 = tab[h3];
    float2 v4 = tab[h4], v5 = tab[h5], v6 = tab[h6], v7 = tab[h7];

    float u0 = 1.f - d0, u1 = 1.f - d1, u2 = 1.f - d2;
    float w0 = u0 * u1 * u2, w1 = d0 * u1 * u2;
    float w2 = u0 * d1 * u2, w3 = u0 * u1 * d2;
    float w4 = d0 * d1 * u2, w5 = d0 * u1 * d2;
    float w6 = u0 * d1 * d2, w7 = d0 * d1 * d2;

    float ex = v0.x * w0, ey = v0.y * w0;
    ex += v1.x * w1;  ey += v1.y * w1;
    ex += v2.x * w2;  ey += v2.y * w2;
    ex += v3.x * w3;  ey += v3.y * w3;
    ex += v4.x * w4;  ey += v4.y * w4;
    ex += v5.x * w5;  ey += v5.y * w5;
    ex += v6.x * w6;  ey += v6.y * w6;
    ex += v7.x * w7;  ey += v7.y * w7;
    float2 o; o.x = ex; o.y = ey; return o;
}

// Each lane = one sorted point; loop level pairs; float4 store to orig row.
__global__ __launch_bounds__(256)
void k_main(const float4* __restrict__ x4, const float2* __restrict__ tab,
            float4* __restrict__ out4, int npts) {
    int ps = blockIdx.x * 256 + threadIdx.x;
    if (ps >= npts) return;
    float4 xo = x4[ps];
    float x0 = xo.x, x1 = xo.y, x2 = xo.z;
    unsigned orig = (unsigned)__float_as_int(xo.w);

    #pragma unroll 1
    for (int j = 0; j < 8; ++j) {
        float2 e0 = enc_level(x0, x1, x2, c_res[2 * j + 0], tab);
        float2 e1 = enc_level(x0, x1, x2, c_res[2 * j + 1], tab);
        float4 o; o.x = e0.x; o.y = e0.y; o.z = e1.x; o.w = e1.y;
        out4[orig * 8 + j] = o;
    }
}

// Fallback (R1 kernel) if ws too small.
__global__ __launch_bounds__(256, 8)
void k_fallback(const float* __restrict__ x, const float2* __restrict__ tab,
                float2* __restrict__ out, int total) {
    int tid = blockIdx.x * 256 + threadIdx.x;
    if (tid >= total) return;
    int p = tid >> 4, l = tid & 15;
    float2 e = enc_level(x[3 * p], x[3 * p + 1], x[3 * p + 2], c_res[l], tab);
    out[tid] = e;
}

extern "C" void kernel_launch(void* const* d_in, const int* in_sizes, int n_in,
                              void* d_out, int out_size, void* d_ws, size_t ws_size,
                              hipStream_t stream)
{
    const float*  x   = (const float*)d_in[0];
    const float2* tab = (const float2*)d_in[1];
    int npts = in_sizes[0] / 3;

    size_t need = 262144 + (size_t)npts * 16;
    if (ws_size < need) {
        int total = npts * 16;
        k_fallback<<<(total + 255) / 256, 256, 0, stream>>>(
            x, tab, (float2*)d_out, total);
        return;
    }

    unsigned* hist   = (unsigned*)d_ws;
    unsigned* cursor = (unsigned*)((char*)d_ws + 131072);
    float4*   x4     = (float4*)((char*)d_ws + 262144);

    k_zero<<<NBUCKET / 256, 256, 0, stream>>>(hist);
    k_hist<<<(npts + 255) / 256, 256, 0, stream>>>(x, hist, npts);
    k_scan<<<1, 1024, 0, stream>>>(hist, cursor);
    k_scatter<<<(npts + 255) / 256, 256, 0, stream>>>(x, cursor, x4, npts);
    k_main<<<(npts + 255) / 256, 256, 0, stream>>>(x4, tab, (float4*)d_out, npts);
}

// Round 4
// 339.002 us; speedup vs baseline: 1.4378x; 1.2686x over previous
//
#include <hip/hip_runtime.h>

// Instant-NGP multires hash encoding fwd. N=1M, L=16, F=2, T=2^19.
// R4: (a) atomic-free counting sort (LDS hist + column scan), permutation only;
//     (b) k_main: one block per res-16 cell; all corners the cell can touch
//         (exact fp box bound, <=4467 over 16 levels) are gathered ONCE into
//         LDS, points interpolate from LDS -> ~8x fewer global gather lanes
//         (the R3 bottleneck was TA lane-address throughput, not bandwidth).

__constant__ float c_res[16] = {
    16.f, 18.f, 21.f, 24.f, 27.f, 32.f, 36.f, 42.f,
    48.f, 55.f, 64.f, 73.f, 84.f, 97.f, 111.f, 128.f
};

#define TMASK   0x7FFFFu
#define PRIME1  2654435761u
#define PRIME2  805459861u
#define NBUCKET 4096          // 16^3 cells
#define NB      128           // sort blocks
#define CACHE_N 4467          // sum over levels of (ceil(r/16)+2)^3 — exact bound

__device__ __forceinline__ int bucket_of(float x0, float x1, float x2) {
    // x*16 is EXACT in fp32 (power-of-2 scale), so cell membership is exact.
    int c0 = (int)(x0 * 16.f); c0 = c0 < 0 ? 0 : (c0 > 15 ? 15 : c0);
    int c1 = (int)(x1 * 16.f); c1 = c1 < 0 ? 0 : (c1 > 15 ? 15 : c1);
    int c2 = (int)(x2 * 16.f); c2 = c2 < 0 ? 0 : (c2 > 15 ? 15 : c2);
    return (c0 << 8) | (c1 << 4) | c2;
}

// ---- sort: per-block LDS histogram, no global atomics anywhere ----

__global__ __launch_bounds__(256)
void k_hist(const float* __restrict__ x, unsigned* __restrict__ cnt, int npts) {
    __shared__ unsigned h[NBUCKET];
    for (int i = threadIdx.x; i < NBUCKET; i += 256) h[i] = 0u;
    __syncthreads();
    int chunk = (npts + NB - 1) / NB;
    int begin = blockIdx.x * chunk;
    int end   = begin + chunk; if (end > npts) end = npts;
    for (int i = begin + threadIdx.x; i < end; i += 256) {
        int b = bucket_of(x[3 * i], x[3 * i + 1], x[3 * i + 2]);
        atomicAdd(&h[b], 1u);          // LDS atomic — cheap
    }
    __syncthreads();
    for (int i = threadIdx.x; i < NBUCKET; i += 256)
        cnt[blockIdx.x * NBUCKET + i] = h[i];
}

// base[b][j] = sum over blocks<b of cnt[.][j]; colsum[j] = column total.
__global__ __launch_bounds__(256)
void k_colscan(const unsigned* __restrict__ cnt, unsigned* __restrict__ base,
               unsigned* __restrict__ colsum) {
    int j = blockIdx.x * 256 + threadIdx.x;   // 0..4095
    unsigned run = 0;
    for (int b = 0; b < NB; ++b) {
        unsigned v = cnt[b * NBUCKET + j];
        base[b * NBUCKET + j] = run;
        run += v;
    }
    colsum[j] = run;
}

// One block: exclusive scan of colsum[4096] -> starts[0..4096].
__global__ __launch_bounds__(1024)
void k_scan(const unsigned* __restrict__ colsum, unsigned* __restrict__ starts) {
    __shared__ unsigned tmp[1024];
    int t = threadIdx.x;
    unsigned v0 = colsum[4 * t + 0], v1 = colsum[4 * t + 1];
    unsigned v2 = colsum[4 * t + 2], v3 = colsum[4 * t + 3];
    unsigned s = v0 + v1 + v2 + v3;
    tmp[t] = s;
    __syncthreads();
    for (int off = 1; off < 1024; off <<= 1) {
        unsigned u = (t >= off) ? tmp[t - off] : 0u;
        __syncthreads();
        tmp[t] += u;
        __syncthreads();
    }
    unsigned excl = tmp[t] - s;
    starts[4 * t + 0] = excl;
    starts[4 * t + 1] = excl + v0;
    starts[4 * t + 2] = excl + v0 + v1;
    starts[4 * t + 3] = excl + v0 + v1 + v2;
    if (t == 1023) starts[4096] = tmp[1023];
}

__global__ __launch_bounds__(256)
void k_scatter(const float* __restrict__ x, const unsigned* __restrict__ base,
               const unsigned* __restrict__ starts, unsigned* __restrict__ perm,
               int npts) {
    __shared__ unsigned cur[NBUCKET];
    for (int i = threadIdx.x; i < NBUCKET; i += 256)
        cur[i] = starts[i] + base[blockIdx.x * NBUCKET + i];
    __syncthreads();
    int chunk = (npts + NB - 1) / NB;
    int begin = blockIdx.x * chunk;
    int end   = begin + chunk; if (end > npts) end = npts;
    for (int i = begin + threadIdx.x; i < end; i += 256) {
        int b = bucket_of(x[3 * i], x[3 * i + 1], x[3 * i + 2]);
        unsigned pos = atomicAdd(&cur[b], 1u);   // LDS atomic
        perm[pos] = (unsigned)i;
    }
}

// ---- main: per-cell LDS corner cache ----
// Box per level for cell i: lo=floor((i/16)*r), hi=ceil(((i+1)/16)*r).
// i*r<=2048 is fp32-exact, /16 dyadic-exact => bounds exact; fp-mul
// monotonicity => every per-point floor/ceil coord lies in [lo,hi].

__global__ __launch_bounds__(256)
void k_main(const float* __restrict__ x, const unsigned* __restrict__ perm,
            const unsigned* __restrict__ starts, const float2* __restrict__ tab,
            float4* __restrict__ out4) {
    __shared__ float2 cache[CACHE_N];

    int cell = blockIdx.x;
    int ci = (cell >> 8) & 15, cj = (cell >> 4) & 15, ck = cell & 15;
    float fi0 = ci * 0.0625f, fi1 = (ci + 1) * 0.0625f;
    float fj0 = cj * 0.0625f, fj1 = (cj + 1) * 0.0625f;
    float fk0 = ck * 0.0625f, fk1 = (ck + 1) * 0.0625f;

    // -------- loader: each unique corner gathered once --------
    int cbase = 0;
    #pragma unroll 1
    for (int l = 0; l < 16; ++l) {
        float r = c_res[l];
        int lo0 = (int)floorf(fi0 * r), hi0 = (int)ceilf(fi1 * r);
        int lo1 = (int)floorf(fj0 * r), hi1 = (int)ceilf(fj1 * r);
        int lo2 = (int)floorf(fk0 * r), hi2 = (int)ceilf(fk1 * r);
        int n0 = hi0 - lo0 + 1, n1 = hi1 - lo1 + 1, n2 = hi2 - lo2 + 1;
        int t = threadIdx.x;
        if (t < n0 * n1) {                         // <=100 threads active
            int a = t / n1, b = t - a * n1;
            unsigned hxy = (unsigned)(lo0 + a)               // *P0(=1)
                         ^ ((unsigned)(lo1 + b) * PRIME1);
            int idx = cbase + t * n2;
            for (int d = 0; d < n2; ++d) {
                unsigned h = (hxy ^ ((unsigned)(lo2 + d) * PRIME2)) & TMASK;
                cache[idx + d] = tab[h];
            }
        }
        cbase += n0 * n1 * n2;
    }
    __syncthreads();

    // -------- interp: all table reads from LDS --------
    int start = starts[cell], end = starts[cell + 1];
    for (int sp = start + (int)threadIdx.x; sp < end; sp += 256) {
        unsigned p = perm[sp];
        float x0 = x[3 * p], x1 = x[3 * p + 1], x2 = x[3 * p + 2];
        float4 o;
        int cb = 0;
        #pragma unroll 1
        for (int l = 0; l < 16; ++l) {
            float r = c_res[l];
            int lo0 = (int)floorf(fi0 * r), hi0 = (int)ceilf(fi1 * r);
            int lo1 = (int)floorf(fj0 * r), hi1 = (int)ceilf(fj1 * r);
            int lo2 = (int)floorf(fk0 * r), hi2 = (int)ceilf(fk1 * r);
            int n0 = hi0 - lo0 + 1, n1 = hi1 - lo1 + 1, n2 = hi2 - lo2 + 1;

            float s0 = x0 * r, s1 = x1 * r, s2 = x2 * r;  // lone mul == numpy
            float f0 = floorf(s0), f1 = floorf(s1), f2 = floorf(s2);
            float d0 = s0 - f0, d1 = s1 - f1, d2 = s2 - f2;
            int A0 = (int)f0 - lo0, B0 = (int)ceilf(s0) - lo0;
            int A1 = (int)f1 - lo1, B1 = (int)ceilf(s1) - lo1;
            int A2 = (int)f2 - lo2, B2 = (int)ceilf(s2) - lo2;

            int rA0 = cb + A0 * n1 * n2, rB0 = cb + B0 * n1 * n2;
            int cA1 = A1 * n2, cB1 = B1 * n2;

            float2 v0 = cache[rA0 + cA1 + A2];   // 000
            float2 v1 = cache[rB0 + cA1 + A2];   // 100
            float2 v2 = cache[rA0 + cB1 + A2];   // 010
            float2 v3 = cache[rA0 + cA1 + B2];   // 001
            float2 v4 = cache[rB0 + cB1 + A2];   // 110
            float2 v5 = cache[rB0 + cA1 + B2];   // 101
            float2 v6 = cache[rA0 + cB1 + B2];   // 011
            float2 v7 = cache[rB0 + cB1 + B2];   // 111

            float u0 = 1.f - d0, u1 = 1.f - d1, u2 = 1.f - d2;
            float w0 = u0 * u1 * u2, w1 = d0 * u1 * u2;
            float w2 = u0 * d1 * u2, w3 = u0 * u1 * d2;
            float w4 = d0 * d1 * u2, w5 = d0 * u1 * d2;
            float w6 = u0 * d1 * d2, w7 = d0 * d1 * d2;

            float ex = v0.x * w0, ey = v0.y * w0;
            ex += v1.x * w1;  ey += v1.y * w1;
            ex += v2.x * w2;  ey += v2.y * w2;
            ex += v3.x * w3;  ey += v3.y * w3;
            ex += v4.x * w4;  ey += v4.y * w4;
            ex += v5.x * w5;  ey += v5.y * w5;
            ex += v6.x * w6;  ey += v6.y * w6;
            ex += v7.x * w7;  ey += v7.y * w7;

            if (l & 1) { o.z = ex; o.w = ey; out4[p * 8 + (l >> 1)] = o; }
            else       { o.x = ex; o.y = ey; }
            cb += n0 * n1 * n2;
        }
    }
}

// Fallback (R1) if ws too small.
__global__ __launch_bounds__(256, 8)
void k_fallback(const float* __restrict__ x, const float2* __restrict__ tab,
                float2* __restrict__ out, int total) {
    int tid = blockIdx.x * 256 + threadIdx.x;
    if (tid >= total) return;
    int p = tid >> 4, l = tid & 15;
    float r = c_res[l];
    float s0 = x[3*p] * r, s1 = x[3*p+1] * r, s2 = x[3*p+2] * r;
    float f0 = floorf(s0), f1 = floorf(s1), f2 = floorf(s2);
    float d0 = s0 - f0, d1 = s1 - f1, d2 = s2 - f2;
    unsigned A0 = (unsigned)(int)f0, B0 = (unsigned)(int)ceilf(s0);
    unsigned A1 = (unsigned)(int)f1 * PRIME1, B1 = (unsigned)(int)ceilf(s1) * PRIME1;
    unsigned A2 = (unsigned)(int)f2 * PRIME2, B2 = (unsigned)(int)ceilf(s2) * PRIME2;
    unsigned h0=(A0^A1^A2)&TMASK, h1=(B0^A1^A2)&TMASK, h2=(A0^B1^A2)&TMASK;
    unsigned h3=(A0^A1^B2)&TMASK, h4=(B0^B1^A2)&TMASK, h5=(B0^A1^B2)&TMASK;
    unsigned h6=(A0^B1^B2)&TMASK, h7=(B0^B1^B2)&TMASK;
    float2 v0=tab[h0],v1=tab[h1],v2=tab[h2],v3=tab[h3];
    float2 v4=tab[h4],v5=tab[h5],v6=tab[h6],v7=tab[h7];
    float u0=1.f-d0,u1=1.f-d1,u2=1.f-d2;
    float ex = v0.x*(u0*u1*u2), ey = v0.y*(u0*u1*u2);
    ex += v1.x*(d0*u1*u2); ey += v1.y*(d0*u1*u2);
    ex += v2.x*(u0*d1*u2); ey += v2.y*(u0*d1*u2);
    ex += v3.x*(u0*u1*d2); ey += v3.y*(u0*u1*d2);
    ex += v4.x*(d0*d1*u2); ey += v4.y*(d0*d1*u2);
    ex += v5.x*(d0*u1*d2); ey += v5.y*(d0*u1*d2);
    ex += v6.x*(u0*d1*d2); ey += v6.y*(u0*d1*d2);
    ex += v7.x*(d0*d1*d2); ey += v7.y*(d0*d1*d2);
    float2 o; o.x = ex; o.y = ey; out[tid] = o;
}

extern "C" void kernel_launch(void* const* d_in, const int* in_sizes, int n_in,
                              void* d_out, int out_size, void* d_ws, size_t ws_size,
                              hipStream_t stream)
{
    const float*  x   = (const float*)d_in[0];
    const float2* tab = (const float2*)d_in[1];
    int npts = in_sizes[0] / 3;

    // ws layout
    size_t off_cnt    = 0;                         // NB*4096 u32 = 2 MB
    size_t off_base   = off_cnt    + (size_t)NB * NBUCKET * 4;   // 2 MB
    size_t off_colsum = off_base   + (size_t)NB * NBUCKET * 4;   // 16 KB
    size_t off_starts = off_colsum + NBUCKET * 4;                // 16 KB + 4
    size_t off_perm   = off_starts + (NBUCKET + 1) * 4 + 60;     // align
    size_t need       = off_perm + (size_t)npts * 4;

    if (ws_size < need) {
        int total = npts * 16;
        k_fallback<<<(total + 255) / 256, 256, 0, stream>>>(
            x, tab, (float2*)d_out, total);
        return;
    }

    unsigned* cnt    = (unsigned*)((char*)d_ws + off_cnt);
    unsigned* base   = (unsigned*)((char*)d_ws + off_base);
    unsigned* colsum = (unsigned*)((char*)d_ws + off_colsum);
    unsigned* starts = (unsigned*)((char*)d_ws + off_starts);
    unsigned* perm   = (unsigned*)((char*)d_ws + off_perm);

    k_hist   <<<NB, 256, 0, stream>>>(x, cnt, npts);
    k_colscan<<<NBUCKET / 256, 256, 0, stream>>>(cnt, base, colsum);
    k_scan   <<<1, 1024, 0, stream>>>(colsum, starts);
    k_scatter<<<NB, 256, 0, stream>>>(x, base, starts, perm, npts);
    k_main   <<<NBUCKET, 256, 0, stream>>>(x, perm, starts, tab,
                                           (float4*)d_out);
}